// Round 2
// baseline (1589.789 us; speedup 1.0000x reference)
//
#include <hip/hip_runtime.h>
#include <stdint.h>

#define N_NODES 100000
#define N_EDGES 3200000

typedef unsigned int u32;
typedef unsigned short u16;
typedef short short8 __attribute__((ext_vector_type(8)));
typedef float f32x4 __attribute__((ext_vector_type(4)));

__device__ __forceinline__ u16 f32_bf16(float f) {
  u32 u = __float_as_uint(f);
  u += 0x7fffu + ((u >> 16) & 1u);   // RNE
  return (u16)(u >> 16);
}
__device__ __forceinline__ float bf16_f32(u16 h) {
  return __uint_as_float(((u32)h) << 16);
}
__device__ __forceinline__ float bf_lo(u32 p) { return __uint_as_float(p << 16); }
__device__ __forceinline__ float bf_hi(u32 p) { return __uint_as_float(p & 0xffff0000u); }

// ---------------- CSR build ----------------
// edge_index arrives as int32 [2][E] (harness converts integer inputs to int32)

__global__ void k_zero(int* counts) {
  int i = blockIdx.x * 256 + threadIdx.x;
  if (i < N_NODES) counts[i] = 0;
}

__global__ void k_count(const int* __restrict__ ei, int* __restrict__ counts) {
  int e = blockIdx.x * 256 + threadIdx.x;
  if (e < N_EDGES) {
    int dst = ei[N_EDGES + e];
    atomicAdd(&counts[dst], 1);
  }
}

__global__ __launch_bounds__(1024) void k_scan(const int* __restrict__ counts,
                                               int* __restrict__ row_start,
                                               int* __restrict__ cursor) {
  __shared__ int partials[1024];
  int t = threadIdx.x;
  const int chunk = 98;  // 1024*98 >= 100000
  int begin = t * chunk;
  int end = begin + chunk;
  if (end > N_NODES) end = N_NODES;
  if (begin > N_NODES) begin = N_NODES;
  int s = 0;
  for (int i = begin; i < end; ++i) s += counts[i];
  partials[t] = s;
  __syncthreads();
  for (int off = 1; off < 1024; off <<= 1) {
    int add = (t >= off) ? partials[t - off] : 0;
    __syncthreads();
    partials[t] += add;
    __syncthreads();
  }
  int run = partials[t] - s;  // exclusive base
  for (int i = begin; i < end; ++i) {
    row_start[i] = run;
    cursor[i] = run;
    run += counts[i];
  }
  if (t == 0) row_start[N_NODES] = N_EDGES;
}

__global__ void k_fill(const int* __restrict__ ei, const float* __restrict__ ew,
                       int* __restrict__ cursor, uint2* __restrict__ entries) {
  int e = blockIdx.x * 256 + threadIdx.x;
  if (e < N_EDGES) {
    int src = ei[e];
    int dst = ei[N_EDGES + e];
    int pos = atomicAdd(&cursor[dst], 1);
    entries[pos] = make_uint2((u32)src, __float_as_uint(ew[e]));
  }
}

// ---------------- W1 transpose+convert: W1t[c][k] bf16 ----------------

__global__ void k_w1t(const float* __restrict__ W1, u16* __restrict__ w1t) {
  int i = blockIdx.x * 256 + threadIdx.x;  // i = c*512 + k
  if (i < 512 * 128) {
    int c = i >> 9, k = i & 511;
    w1t[i] = f32_bf16(W1[k * 128 + c]);
  }
}

// ---------------- GEMM1: support1[N][128] bf16 = x @ W1 (MFMA 16x16x32) ----
// A operand = W1 columns (from W1t), B operand = x rows (converted in-reg).
// D[m=Wcol][n=xrow]; C-layout: col=lane&15 (xrow), row=(lane>>4)*4+reg (Wcol).

__global__ __launch_bounds__(256) void k_gemm1(const float* __restrict__ x,
                                               const u16* __restrict__ w1t,
                                               u16* __restrict__ s1) {
  int wid = threadIdx.x >> 6, lane = threadIdx.x & 63;
  int tile = blockIdx.x * 4 + wid;  // 16-row tile of x
  if (tile * 16 >= N_NODES) return;
  int r0 = tile * 16;
  int m = lane & 15;       // x row within tile / W col within tile
  int kg = lane >> 4;      // k-group 0..3
  const float* xp = x + (size_t)(r0 + m) * 512 + kg * 8;
  const u16* wp = w1t + (size_t)m * 512 + kg * 8;

  f32x4 acc[8] = {};
#pragma unroll 2
  for (int kk = 0; kk < 512; kk += 32) {
    f32x4 a0 = *(const f32x4*)(xp + kk);
    f32x4 a1 = *(const f32x4*)(xp + kk + 4);
    short8 bfrag;
    bfrag[0] = (short)f32_bf16(a0[0]);
    bfrag[1] = (short)f32_bf16(a0[1]);
    bfrag[2] = (short)f32_bf16(a0[2]);
    bfrag[3] = (short)f32_bf16(a0[3]);
    bfrag[4] = (short)f32_bf16(a1[0]);
    bfrag[5] = (short)f32_bf16(a1[1]);
    bfrag[6] = (short)f32_bf16(a1[2]);
    bfrag[7] = (short)f32_bf16(a1[3]);
#pragma unroll
    for (int t = 0; t < 8; ++t) {
      short8 afrag = *(const short8*)(wp + (size_t)t * 16 * 512 + kk);
      acc[t] = __builtin_amdgcn_mfma_f32_16x16x32_bf16(afrag, bfrag, acc[t], 0, 0, 0);
    }
  }
  int row = r0 + m;
#pragma unroll
  for (int t = 0; t < 8; ++t) {
    uint2 pk;
    pk.x = (u32)f32_bf16(acc[t][0]) | ((u32)f32_bf16(acc[t][1]) << 16);
    pk.y = (u32)f32_bf16(acc[t][2]) | ((u32)f32_bf16(acc[t][3]) << 16);
    *(uint2*)(s1 + (size_t)row * 128 + t * 16 + kg * 4) = pk;
  }
}

// ---------------- layer-1 aggregate + bias + relu -> h[N][128] bf16 --------
// one wave per dst node; lane handles dims 2*lane, 2*lane+1

__global__ __launch_bounds__(256) void k_agg1(const uint2* __restrict__ entries,
                                              const int* __restrict__ row_start,
                                              const u32* __restrict__ s1u,
                                              const float* __restrict__ b1,
                                              u32* __restrict__ h_out) {
  int wid = threadIdx.x >> 6, lane = threadIdx.x & 63;
  int dst = blockIdx.x * 4 + wid;
  if (dst >= N_NODES) return;
  int beg = row_start[dst], end = row_start[dst + 1];
  float acc0 = 0.f, acc1 = 0.f;
  for (int i = beg; i < end; ++i) {
    uint2 ent = entries[i];
    float w = __uint_as_float(ent.y);
    u32 p = s1u[(size_t)ent.x * 64 + lane];
    acc0 += w * bf_lo(p);
    acc1 += w * bf_hi(p);
  }
  float2 bb = *(const float2*)(b1 + 2 * lane);
  float h0 = fmaxf(acc0 + bb.x, 0.f);
  float h1 = fmaxf(acc1 + bb.y, 0.f);
  h_out[(size_t)dst * 64 + lane] = (u32)f32_bf16(h0) | ((u32)f32_bf16(h1) << 16);
}

// ---------------- GEMM2: support2[N][40] bf16 = h @ W2 (vector fp32) -------
// block = 320 threads = 8 rows x 40 cols; W2 staged in LDS

__global__ __launch_bounds__(320) void k_gemm2(const u16* __restrict__ h,
                                               const float* __restrict__ W2,
                                               u16* __restrict__ s2) {
  __shared__ float w2s[128 * 40];
  for (int i = threadIdx.x; i < 128 * 40; i += 320) w2s[i] = W2[i];
  __syncthreads();
  int r = blockIdx.x * 8 + threadIdx.x / 40;
  int c = threadIdx.x % 40;
  const u32* hrow = (const u32*)(h + (size_t)r * 128);
  float acc = 0.f;
#pragma unroll 8
  for (int k2 = 0; k2 < 64; ++k2) {
    u32 p = hrow[k2];
    acc += bf_lo(p) * w2s[(2 * k2) * 40 + c];
    acc += bf_hi(p) * w2s[(2 * k2 + 1) * 40 + c];
  }
  s2[(size_t)r * 40 + c] = f32_bf16(acc);
}

// ---------------- layer-2 aggregate + bias + log_softmax -> out ------------
// one wave per dst node; lanes 0..39 active

__global__ __launch_bounds__(256) void k_agg2(const uint2* __restrict__ entries,
                                              const int* __restrict__ row_start,
                                              const u16* __restrict__ s2,
                                              const float* __restrict__ b2,
                                              float* __restrict__ out) {
  int wid = threadIdx.x >> 6, lane = threadIdx.x & 63;
  int dst = blockIdx.x * 4 + wid;
  if (dst >= N_NODES) return;
  int beg = row_start[dst], end = row_start[dst + 1];
  bool active = lane < 40;
  float acc = 0.f;
  for (int i = beg; i < end; ++i) {
    uint2 ent = entries[i];
    float w = __uint_as_float(ent.y);
    float v = 0.f;
    if (active) v = bf16_f32(s2[(size_t)ent.x * 40 + lane]);
    acc += w * v;
  }
  float v = active ? (acc + b2[lane]) : -INFINITY;
  float mx = v;
#pragma unroll
  for (int off = 32; off > 0; off >>= 1) mx = fmaxf(mx, __shfl_xor(mx, off));
  float e = active ? __expf(v - mx) : 0.f;
  float sum = e;
#pragma unroll
  for (int off = 32; off > 0; off >>= 1) sum += __shfl_xor(sum, off);
  if (active) out[(size_t)dst * 40 + lane] = (v - mx) - __logf(sum);
}

// ---------------- launch ----------------

extern "C" void kernel_launch(void* const* d_in, const int* in_sizes, int n_in,
                              void* d_out, int out_size, void* d_ws, size_t ws_size,
                              hipStream_t stream) {
  const float* x = (const float*)d_in[0];
  const int* ei = (const int*)d_in[1];     // int32 [2][E]
  const float* ew = (const float*)d_in[2];
  const float* W1 = (const float*)d_in[3];
  const float* b1 = (const float*)d_in[4];
  const float* W2 = (const float*)d_in[5];
  const float* b2 = (const float*)d_in[6];
  float* out = (float*)d_out;

  char* p = (char*)d_ws;
  u16* w1t = (u16*)p;           p += 128 * 512 * 2;                 // 128 KiB
  int* counts = (int*)p;        p += 100096 * 4;
  int* row_start = (int*)p;     p += 100096 * 4;
  int* cursor = (int*)p;        p += 100096 * 4;
  uint2* entries = (uint2*)p;   p += (size_t)N_EDGES * 8;           // 25.6 MB
  u16* s1 = (u16*)p;            p += (size_t)N_NODES * 128 * 2;     // 25.6 MB
  u16* h = (u16*)p;             p += (size_t)N_NODES * 128 * 2;     // 25.6 MB
  u16* s2 = s1;  // support1 is dead after k_agg1; alias

  k_zero<<<(N_NODES + 255) / 256, 256, 0, stream>>>(counts);
  k_w1t<<<(512 * 128) / 256, 256, 0, stream>>>(W1, w1t);
  k_count<<<N_EDGES / 256, 256, 0, stream>>>(ei, counts);
  k_scan<<<1, 1024, 0, stream>>>(counts, row_start, cursor);
  k_fill<<<N_EDGES / 256, 256, 0, stream>>>(ei, ew, cursor, entries);
  k_gemm1<<<(6250 + 3) / 4, 256, 0, stream>>>(x, w1t, s1);
  k_agg1<<<N_NODES / 4, 256, 0, stream>>>(entries, row_start, (const u32*)s1, b1, (u32*)h);
  k_gemm2<<<N_NODES / 8, 320, 0, stream>>>(h, W2, s2);
  k_agg2<<<N_NODES / 4, 256, 0, stream>>>(entries, row_start, s2, b2, out);
}

// Round 3
// 1003.994 us; speedup vs baseline: 1.5835x; 1.5835x over previous
//
#include <hip/hip_runtime.h>
#include <stdint.h>

#define N_NODES 100000
#define N_EDGES 3200000

typedef unsigned int u32;
typedef unsigned short u16;
typedef short short8 __attribute__((ext_vector_type(8)));
typedef float f32x4 __attribute__((ext_vector_type(4)));

__device__ __forceinline__ u16 f32_bf16(float f) {
  u32 u = __float_as_uint(f);
  u += 0x7fffu + ((u >> 16) & 1u);   // RNE
  return (u16)(u >> 16);
}
__device__ __forceinline__ float bf16_f32(u16 h) {
  return __uint_as_float(((u32)h) << 16);
}
__device__ __forceinline__ float bf_lo(u32 p) { return __uint_as_float(p << 16); }
__device__ __forceinline__ float bf_hi(u32 p) { return __uint_as_float(p & 0xffff0000u); }

// ---------------- CSR build ----------------
// edge_index arrives as int32 [2][E]

__global__ void k_zero(int* counts) {
  int i = blockIdx.x * 256 + threadIdx.x;
  if (i < N_NODES) counts[i] = 0;
}

__global__ void k_count(const int* __restrict__ ei, int* __restrict__ counts) {
  int e4 = blockIdx.x * 256 + threadIdx.x;
  if (e4 * 4 < N_EDGES) {
    int4 d = *(const int4*)(ei + N_EDGES + e4 * 4);
    atomicAdd(&counts[d.x], 1);
    atomicAdd(&counts[d.y], 1);
    atomicAdd(&counts[d.z], 1);
    atomicAdd(&counts[d.w], 1);
  }
}

// block-level exclusive scan: 98 blocks x 1024
__global__ __launch_bounds__(1024) void k_scanA(const int* __restrict__ counts,
                                                int* __restrict__ row_start,
                                                int* __restrict__ block_tot) {
  __shared__ int sm[1024];
  int t = threadIdx.x;
  int g = blockIdx.x * 1024 + t;
  int v = (g < N_NODES) ? counts[g] : 0;
  sm[t] = v;
  __syncthreads();
  for (int off = 1; off < 1024; off <<= 1) {
    int add = (t >= off) ? sm[t - off] : 0;
    __syncthreads();
    sm[t] += add;
    __syncthreads();
  }
  if (g < N_NODES) row_start[g] = sm[t] - v;  // exclusive, no block prefix yet
  if (t == 1023) block_tot[blockIdx.x] = sm[t];
}

__global__ __launch_bounds__(128) void k_scanB(const int* __restrict__ block_tot,
                                               int* __restrict__ block_pref) {
  __shared__ int sm[128];
  int t = threadIdx.x;
  int v = (t < 98) ? block_tot[t] : 0;
  sm[t] = v;
  __syncthreads();
  for (int off = 1; off < 128; off <<= 1) {
    int add = (t >= off) ? sm[t - off] : 0;
    __syncthreads();
    sm[t] += add;
    __syncthreads();
  }
  if (t < 98) block_pref[t] = sm[t] - v;  // exclusive
}

__global__ __launch_bounds__(1024) void k_scanC(int* __restrict__ row_start,
                                                const int* __restrict__ block_pref,
                                                int* __restrict__ cursor) {
  int t = threadIdx.x;
  int g = blockIdx.x * 1024 + t;
  if (g < N_NODES) {
    int rs = row_start[g] + block_pref[blockIdx.x];
    row_start[g] = rs;
    cursor[g] = rs;
  }
  if (g == 0) row_start[N_NODES] = N_EDGES;
}

__global__ void k_fill(const int* __restrict__ ei, const float* __restrict__ ew,
                       int* __restrict__ cursor, uint2* __restrict__ entries) {
  int e4 = blockIdx.x * 256 + threadIdx.x;
  if (e4 * 4 < N_EDGES) {
    int4 s = *(const int4*)(ei + e4 * 4);
    int4 d = *(const int4*)(ei + N_EDGES + e4 * 4);
    f32x4 w = *(const f32x4*)(ew + e4 * 4);
    int p0 = atomicAdd(&cursor[d.x], 1);
    int p1 = atomicAdd(&cursor[d.y], 1);
    int p2 = atomicAdd(&cursor[d.z], 1);
    int p3 = atomicAdd(&cursor[d.w], 1);
    entries[p0] = make_uint2((u32)s.x, __float_as_uint(w[0]));
    entries[p1] = make_uint2((u32)s.y, __float_as_uint(w[1]));
    entries[p2] = make_uint2((u32)s.z, __float_as_uint(w[2]));
    entries[p3] = make_uint2((u32)s.w, __float_as_uint(w[3]));
  }
}

// ---------------- W1 transpose+convert: W1t[c][k] bf16 ----------------

__global__ void k_w1t(const float* __restrict__ W1, u16* __restrict__ w1t) {
  int i = blockIdx.x * 256 + threadIdx.x;  // i = c*512 + k
  if (i < 512 * 128) {
    int c = i >> 9, k = i & 511;
    w1t[i] = f32_bf16(W1[k * 128 + c]);
  }
}

// ---------------- GEMM1: support1[N][128] bf16 = x @ W1 (MFMA 16x16x32) ----

__global__ __launch_bounds__(256) void k_gemm1(const float* __restrict__ x,
                                               const u16* __restrict__ w1t,
                                               u16* __restrict__ s1) {
  int wid = threadIdx.x >> 6, lane = threadIdx.x & 63;
  int tile = blockIdx.x * 4 + wid;  // 16-row tile of x
  if (tile * 16 >= N_NODES) return;
  int r0 = tile * 16;
  int m = lane & 15;
  int kg = lane >> 4;
  const float* xp = x + (size_t)(r0 + m) * 512 + kg * 8;
  const u16* wp = w1t + (size_t)m * 512 + kg * 8;

  f32x4 acc[8] = {};
#pragma unroll 2
  for (int kk = 0; kk < 512; kk += 32) {
    f32x4 a0 = *(const f32x4*)(xp + kk);
    f32x4 a1 = *(const f32x4*)(xp + kk + 4);
    short8 bfrag;
    bfrag[0] = (short)f32_bf16(a0[0]);
    bfrag[1] = (short)f32_bf16(a0[1]);
    bfrag[2] = (short)f32_bf16(a0[2]);
    bfrag[3] = (short)f32_bf16(a0[3]);
    bfrag[4] = (short)f32_bf16(a1[0]);
    bfrag[5] = (short)f32_bf16(a1[1]);
    bfrag[6] = (short)f32_bf16(a1[2]);
    bfrag[7] = (short)f32_bf16(a1[3]);
#pragma unroll
    for (int t = 0; t < 8; ++t) {
      short8 afrag = *(const short8*)(wp + (size_t)t * 16 * 512 + kk);
      acc[t] = __builtin_amdgcn_mfma_f32_16x16x32_bf16(afrag, bfrag, acc[t], 0, 0, 0);
    }
  }
  int row = r0 + m;
#pragma unroll
  for (int t = 0; t < 8; ++t) {
    uint2 pk;
    pk.x = (u32)f32_bf16(acc[t][0]) | ((u32)f32_bf16(acc[t][1]) << 16);
    pk.y = (u32)f32_bf16(acc[t][2]) | ((u32)f32_bf16(acc[t][3]) << 16);
    *(uint2*)(s1 + (size_t)row * 128 + t * 16 + kg * 4) = pk;
  }
}

// ---------------- layer-1 aggregate + bias + relu -> h[N][128] bf16 --------
// one wave per dst; 2 edges per wave-instruction (lane halves), unroll x2.
// lane l: half = l>>5 picks edge of pair, q = l&31 covers dims 4q..4q+3 (uint2)

__global__ __launch_bounds__(256) void k_agg1(const uint2* __restrict__ entries,
                                              const int* __restrict__ row_start,
                                              const uint2* __restrict__ s1u2,
                                              const float* __restrict__ b1,
                                              uint2* __restrict__ h_u2) {
  int wid = threadIdx.x >> 6, lane = threadIdx.x & 63;
  int dst = __builtin_amdgcn_readfirstlane(blockIdx.x * 4 + wid);
  if (dst >= N_NODES) return;
  int beg = row_start[dst], end = row_start[dst + 1];
  int half = lane >> 5, q = lane & 31;
  float a0 = 0.f, a1 = 0.f, a2 = 0.f, a3 = 0.f;
  int i = beg;
  // main loop: 4 edges, no guards
  for (; i + 4 <= end; i += 4) {
    uint2 e0 = entries[i], e1 = entries[i + 1], e2 = entries[i + 2], e3 = entries[i + 3];
    u32 srcA = half ? e1.x : e0.x;
    float wA = __uint_as_float(half ? e1.y : e0.y);
    u32 srcB = half ? e3.x : e2.x;
    float wB = __uint_as_float(half ? e3.y : e2.y);
    uint2 pA = s1u2[(size_t)srcA * 32 + q];
    uint2 pB = s1u2[(size_t)srcB * 32 + q];
    a0 += wA * bf_lo(pA.x); a1 += wA * bf_hi(pA.x);
    a2 += wA * bf_lo(pA.y); a3 += wA * bf_hi(pA.y);
    a0 += wB * bf_lo(pB.x); a1 += wB * bf_hi(pB.x);
    a2 += wB * bf_lo(pB.y); a3 += wB * bf_hi(pB.y);
  }
  // tail: pairs with guard
  for (; i < end; i += 2) {
    uint2 e0 = entries[i];
    uint2 e1 = (i + 1 < end) ? entries[i + 1] : make_uint2(e0.x, 0u);
    u32 srcA = half ? e1.x : e0.x;
    float wA = __uint_as_float(half ? e1.y : e0.y);
    uint2 pA = s1u2[(size_t)srcA * 32 + q];
    a0 += wA * bf_lo(pA.x); a1 += wA * bf_hi(pA.x);
    a2 += wA * bf_lo(pA.y); a3 += wA * bf_hi(pA.y);
  }
  // combine halves
  a0 += __shfl_xor(a0, 32);
  a1 += __shfl_xor(a1, 32);
  a2 += __shfl_xor(a2, 32);
  a3 += __shfl_xor(a3, 32);
  if (half == 0) {
    f32x4 bb = *(const f32x4*)(b1 + 4 * q);
    float h0 = fmaxf(a0 + bb[0], 0.f);
    float h1 = fmaxf(a1 + bb[1], 0.f);
    float h2 = fmaxf(a2 + bb[2], 0.f);
    float h3 = fmaxf(a3 + bb[3], 0.f);
    uint2 pk;
    pk.x = (u32)f32_bf16(h0) | ((u32)f32_bf16(h1) << 16);
    pk.y = (u32)f32_bf16(h2) | ((u32)f32_bf16(h3) << 16);
    h_u2[(size_t)dst * 32 + q] = pk;
  }
}

// ---------------- GEMM2: support2[N][40] bf16 = h @ W2 (vector fp32) -------

__global__ __launch_bounds__(320) void k_gemm2(const u16* __restrict__ h,
                                               const float* __restrict__ W2,
                                               u16* __restrict__ s2) {
  __shared__ float w2s[128 * 40];
  for (int i = threadIdx.x; i < 128 * 40; i += 320) w2s[i] = W2[i];
  __syncthreads();
  int r = blockIdx.x * 8 + threadIdx.x / 40;
  int c = threadIdx.x % 40;
  const u32* hrow = (const u32*)(h + (size_t)r * 128);
  float acc = 0.f;
#pragma unroll 8
  for (int k2 = 0; k2 < 64; ++k2) {
    u32 p = hrow[k2];
    acc += bf_lo(p) * w2s[(2 * k2) * 40 + c];
    acc += bf_hi(p) * w2s[(2 * k2 + 1) * 40 + c];
  }
  s2[(size_t)r * 40 + c] = f32_bf16(acc);
}

// ---------------- layer-2 aggregate + bias + log_softmax -> out ------------
// one wave per dst; 3 edges per wave-instruction (20 lanes x u32 each), unroll x2.
// lane l: g = l/20 (edge in triple), d = l%20 (u32 index = dims 2d,2d+1)

__global__ __launch_bounds__(256) void k_agg2(const uint2* __restrict__ entries,
                                              const int* __restrict__ row_start,
                                              const u32* __restrict__ s2u,
                                              const float* __restrict__ b2,
                                              float* __restrict__ out) {
  int wid = threadIdx.x >> 6, lane = threadIdx.x & 63;
  int dst = __builtin_amdgcn_readfirstlane(blockIdx.x * 4 + wid);
  if (dst >= N_NODES) return;
  int beg = row_start[dst], end = row_start[dst + 1];
  u32 g = (u32)lane / 20u;
  u32 d = (u32)lane - 20u * g;
  float a0 = 0.f, a1 = 0.f;
  int i = beg;
  for (; i + 6 <= end; i += 6) {
    uint2 e0 = entries[i],     e1 = entries[i + 1], e2 = entries[i + 2];
    uint2 e3 = entries[i + 3], e4 = entries[i + 4], e5 = entries[i + 5];
    u32 sA = (g == 0) ? e0.x : ((g == 1) ? e1.x : e2.x);
    u32 wAu = (g == 0) ? e0.y : ((g == 1) ? e1.y : e2.y);
    u32 sB = (g == 0) ? e3.x : ((g == 1) ? e4.x : e5.x);
    u32 wBu = (g == 0) ? e3.y : ((g == 1) ? e4.y : e5.y);
    u32 pA = s2u[(size_t)sA * 20 + d];
    u32 pB = s2u[(size_t)sB * 20 + d];
    float wA = __uint_as_float(wAu), wB = __uint_as_float(wBu);
    a0 += wA * bf_lo(pA); a1 += wA * bf_hi(pA);
    a0 += wB * bf_lo(pB); a1 += wB * bf_hi(pB);
  }
  for (; i < end; i += 3) {
    uint2 e0 = entries[i];
    uint2 e1 = (i + 1 < end) ? entries[i + 1] : make_uint2(e0.x, 0u);
    uint2 e2 = (i + 2 < end) ? entries[i + 2] : make_uint2(e0.x, 0u);
    u32 sA = (g == 0) ? e0.x : ((g == 1) ? e1.x : e2.x);
    u32 wAu = (g == 0) ? e0.y : ((g == 1) ? e1.y : e2.y);
    u32 pA = s2u[(size_t)sA * 20 + d];
    float wA = __uint_as_float(wAu);
    a0 += wA * bf_lo(pA); a1 += wA * bf_hi(pA);
  }
  // combine 3 groups into lanes 0..19
  a0 += __shfl(a0, lane + 20) + __shfl(a0, lane + 40);
  a1 += __shfl(a1, lane + 20) + __shfl(a1, lane + 40);
  bool act = lane < 20;
  float v0 = -INFINITY, v1 = -INFINITY;
  if (act) {
    float2 bb = *(const float2*)(b2 + 2 * d);
    v0 = a0 + bb.x;
    v1 = a1 + bb.y;
  }
  float mx = fmaxf(v0, v1);
#pragma unroll
  for (int off = 16; off > 0; off >>= 1) mx = fmaxf(mx, __shfl_xor(mx, off));
  float e = act ? (__expf(v0 - mx) + __expf(v1 - mx)) : 0.f;
#pragma unroll
  for (int off = 16; off > 0; off >>= 1) e += __shfl_xor(e, off);
  if (act) {
    float ls = __logf(e);
    float2 o = make_float2((v0 - mx) - ls, (v1 - mx) - ls);
    *(float2*)(out + (size_t)dst * 40 + 2 * d) = o;
  }
}

// ---------------- launch ----------------

extern "C" void kernel_launch(void* const* d_in, const int* in_sizes, int n_in,
                              void* d_out, int out_size, void* d_ws, size_t ws_size,
                              hipStream_t stream) {
  const float* x = (const float*)d_in[0];
  const int* ei = (const int*)d_in[1];     // int32 [2][E]
  const float* ew = (const float*)d_in[2];
  const float* W1 = (const float*)d_in[3];
  const float* b1 = (const float*)d_in[4];
  const float* W2 = (const float*)d_in[5];
  const float* b2 = (const float*)d_in[6];
  float* out = (float*)d_out;

  char* p = (char*)d_ws;
  u16* w1t = (u16*)p;           p += 128 * 512 * 2;                 // 128 KiB
  int* counts = (int*)p;        p += 100096 * 4;
  int* row_start = (int*)p;     p += 100096 * 4;
  int* cursor = (int*)p;        p += 100096 * 4;
  int* block_tot = (int*)p;     p += 128 * 4;
  int* block_pref = (int*)p;    p += 128 * 4;
  uint2* entries = (uint2*)p;   p += (size_t)N_EDGES * 8;           // 25.6 MB
  u16* s1 = (u16*)p;            p += (size_t)N_NODES * 128 * 2;     // 25.6 MB
  u16* h = (u16*)p;             p += (size_t)N_NODES * 128 * 2;     // 25.6 MB
  u16* s2 = s1;  // support1 is dead after k_agg1; alias

  k_zero<<<(N_NODES + 255) / 256, 256, 0, stream>>>(counts);
  k_w1t<<<(512 * 128) / 256, 256, 0, stream>>>(W1, w1t);
  k_count<<<N_EDGES / 4 / 256, 256, 0, stream>>>(ei, counts);
  k_scanA<<<98, 1024, 0, stream>>>(counts, row_start, block_tot);
  k_scanB<<<1, 128, 0, stream>>>(block_tot, block_pref);
  k_scanC<<<98, 1024, 0, stream>>>(row_start, block_pref, cursor);
  k_fill<<<N_EDGES / 4 / 256, 256, 0, stream>>>(ei, ew, cursor, entries);
  k_gemm1<<<(6250 + 3) / 4, 256, 0, stream>>>(x, w1t, s1);
  k_agg1<<<N_NODES / 4, 256, 0, stream>>>(entries, row_start, (const uint2*)s1, b1, (uint2*)h);
  k_gemm2<<<N_NODES / 8, 320, 0, stream>>>(h, W2, s2);
  k_agg2<<<N_NODES / 4, 256, 0, stream>>>(entries, row_start, (const u32*)s2, b2, out);
}